// Round 3
// baseline (23673.961 us; speedup 1.0000x reference)
//
#include <hip/hip_runtime.h>
#include <cstddef>

// SimpleLSTM: B=64, D=512, T=512, H=1024, O=1 — fp16, fixed ws layout
// ws layout (needs ~46.4 MB):
//   [0, 32MB)            xT: f16 [T=512][B=64][D=512]                  = 33,554,432 B
//   [32MB, +12.58MB)     Wf: f16 A-frags [r=64][w=8][kl=6][mt=4][64][8] = 12,582,912 B
//   [46,137,344, +256KB) h double buffer: f16 [2][B=64][H=1024]        =    262,144 B
//   [46,399,488, +512B)  group counters (128B-strided)
#define WS_XT_OFF   0ull
#define WS_WF_OFF   33554432ull
#define WS_HB_OFF   46137344ull
#define WS_CTR_OFF  46399488ull

typedef _Float16 f16x8 __attribute__((ext_vector_type(8)));
typedef float    f32x4 __attribute__((ext_vector_type(4)));
typedef unsigned short u16;
typedef unsigned int   u32;

__device__ __forceinline__ u16 f2h(float f) {
  _Float16 h = (_Float16)f;                     // v_cvt_f16_f32, RNE
  return __builtin_bit_cast(u16, h);
}
__device__ __forceinline__ float sigm(float x) { return 1.0f / (1.0f + __expf(-x)); }

// ---------- K0: init out=b_out, h buf0 = 0, counters = 0 ----------
__global__ __launch_bounds__(256) void k_init(u16* hbuf, u32* ctrs, float* out,
                                              const float* __restrict__ b_out) {
  int t = blockIdx.x * 256 + threadIdx.x;       // 32768 threads
  ((u32*)hbuf)[t] = 0u;                         // zeroes buf0 (131072 B)
  out[t] = b_out[0];                            // 64*512 outputs
  if (t < 128) ctrs[t] = 0u;
}

// ---------- K1: x (B,D,T) f32 -> xT[t][b][d] f16 ----------
__global__ __launch_bounds__(256) void k_xpose(const float* __restrict__ x,
                                               u16* __restrict__ xT) {
  __shared__ float lds[64][65];
  const int d0 = blockIdx.x * 64, t0 = blockIdx.y * 64, b = blockIdx.z;
  const int tid = threadIdx.x;
  const int tt = tid & 63, dr = tid >> 6;
  const float* xp = x + ((size_t)b * 512 + d0) * 512 + t0 + tt;
#pragma unroll
  for (int i = 0; i < 16; ++i) {
    int dd = i * 4 + dr;
    lds[dd][tt] = xp[(size_t)dd * 512];
  }
  __syncthreads();
  const int dp = tid & 31, rr = tid >> 5;
#pragma unroll
  for (int i = 0; i < 8; ++i) {
    int tt2 = i * 8 + rr;
    u32 lo = f2h(lds[dp * 2][tt2]);
    u32 hi = f2h(lds[dp * 2 + 1][tt2]);
    *(u32*)(xT + ((size_t)(t0 + tt2) * 64 + b) * 512 + d0 + dp * 2) = lo | (hi << 16);
  }
}

// ---------- K2: pack [W_ih | W_hh] rows into per-lane MFMA A-fragments (f16) ----------
// chunk c = ((r*8+w)*6+kl)*4+mt ; within-tile row m: gate=m&3, j=r*16+mt*4+(m>>2)
__global__ __launch_bounds__(256) void k_wfrag(const float* __restrict__ W_ih,
                                               const float* __restrict__ W_hh,
                                               u16* __restrict__ Wf) {
  int g = blockIdx.x * 256 + threadIdx.x;       // 786432 threads
  int lane = g & 63;
  int c  = g >> 6;
  int mt = c & 3;
  int c2 = c >> 2;
  int kl = c2 % 6;
  int c3 = c2 / 6;
  int wv = c3 & 7;
  int r  = c3 >> 3;
  int m = lane & 15, q = lane >> 4;
  int gate = m & 3;
  int j = r * 16 + mt * 4 + (m >> 2);
  int row = gate * 1024 + j;
  int ks = wv * 6 + kl;
  const float* src = (ks < 16) ? (W_ih + (size_t)row * 512 + ks * 32 + q * 8)
                               : (W_hh + (size_t)row * 1024 + (ks - 16) * 32 + q * 8);
  union { u16 s[8]; uint4 v; } U;
#pragma unroll
  for (int i = 0; i < 8; ++i) U.s[i] = f2h(src[i]);
  *(uint4*)(Wf + ((size_t)c * 64 + lane) * 8) = U.v;
}

// ---------- K3: persistent cooperative recurrence ----------
// grid 256 = 4 groups x 64 blocks; block 512 = 8 waves; 1 block/CU.
__global__ __launch_bounds__(512, 2) void k_lstm(
    const u16* __restrict__ xT, const u16* __restrict__ Wf,
    u16* hbuf, u32* ctrs,
    const float* __restrict__ b_ih, const float* __restrict__ b_hh,
    const float* __restrict__ W_out, float* __restrict__ out) {
  __shared__ float red[8 * 4 * 64 * 4];   // [wave][mt][lane][4] partial accs, 32 KB
  __shared__ float outred[64];            // [mt][16b]
  const int tid = threadIdx.x;
  const int w = tid >> 6, lane = tid & 63;
  const int blk = blockIdx.x, g = blk >> 6, r = blk & 63;
  const int bg0 = g * 16, j0 = r * 16;
  const int n = lane & 15, q = lane >> 4;

  // Step-invariant weights -> registers (96 VGPR/lane)
  f16x8 wfr[6][4];
#pragma unroll
  for (int kl = 0; kl < 6; ++kl)
#pragma unroll
    for (int mt = 0; mt < 4; ++mt) {
      size_t c = ((size_t)(r * 8 + w) * 6 + kl) * 4 + mt;
      wfr[kl][mt] = *(const f16x8*)(Wf + (c * 64 + lane) * 8);
    }

  float bias0 = 0.f, bias1 = 0.f, bias2 = 0.f, bias3 = 0.f, wout = 0.f;
  if (w < 4) {
    int j = j0 + w * 4 + q;
    bias0 = b_ih[j]        + b_hh[j];
    bias1 = b_ih[1024 + j] + b_hh[1024 + j];
    bias2 = b_ih[2048 + j] + b_hh[2048 + j];
    bias3 = b_ih[3072 + j] + b_hh[3072 + j];
    wout  = W_out[j];
  }

  u16* hb0 = hbuf;
  u16* hb1 = hbuf + 64 * 1024;
  u32* ctr = ctrs + g * 32;               // 128-B separated per group
  float c_state = 0.f;
  const f32x4 zero = {0.f, 0.f, 0.f, 0.f};

  for (int t = 0; t < 512; ++t) {
    // waves holding h k-steps wait until all 64 group blocks finished step t-1
    if (w >= 2 && t > 0) {
      u32 target = (u32)(64 * t);
      while (__hip_atomic_load(ctr, __ATOMIC_RELAXED, __HIP_MEMORY_SCOPE_AGENT) < target)
        __builtin_amdgcn_s_sleep(1);
      __threadfence();   // acquire side: invalidate caches, order h loads after spin
    }
    const u16* hcur = (t & 1) ? hb1 : hb0;
    u16* hnext      = (t & 1) ? hb0 : hb1;
    const u16* xtb  = xT + (size_t)t * 32768;

    // B-fragments: [x_t ; h_t] for this wave's 6 k-steps (plain 16B loads)
    f16x8 bfr[6];
#pragma unroll
    for (int kl = 0; kl < 6; ++kl) {
      int ks = w * 6 + kl;
      if (ks < 16) {
        bfr[kl] = *(const f16x8*)(xtb + (bg0 + n) * 512 + ks * 32 + q * 8);
      } else {
        bfr[kl] = *(const f16x8*)(hcur + (bg0 + n) * 1024 + (ks - 16) * 32 + q * 8);
      }
    }

    f32x4 acc[4];
#pragma unroll
    for (int mt = 0; mt < 4; ++mt) acc[mt] = zero;
#pragma unroll
    for (int kl = 0; kl < 6; ++kl)
#pragma unroll
      for (int mt = 0; mt < 4; ++mt)
        acc[mt] = __builtin_amdgcn_mfma_f32_16x16x32_f16(wfr[kl][mt], bfr[kl], acc[mt], 0, 0, 0);

#pragma unroll
    for (int mt = 0; mt < 4; ++mt)
      *(f32x4*)&red[((w * 4 + mt) * 64 + lane) * 4] = acc[mt];
    __syncthreads();

    if (w < 4) {
      const int mt = w;
      f32x4 s = zero;
#pragma unroll
      for (int wv = 0; wv < 8; ++wv)
        s += *(const f32x4*)&red[((wv * 4 + mt) * 64 + lane) * 4];
      // lane owns all 4 gates of (b = bg0+n, j = j0+mt*4+q): regs = i,f,g,o
      float gi = s.x + bias0, gf = s.y + bias1, gg = s.z + bias2, go = s.w + bias3;
      c_state = sigm(gf) * c_state + sigm(gi) * tanhf(gg);
      float h = sigm(go) * tanhf(c_state);
      // pack f16 pairs across quads and store to hnext[b][j]
      u32 hv = (u32)f2h(h);
      u32 other = (u32)__shfl_xor((int)hv, 16);
      if ((q & 1) == 0) {
        u32 packed = (hv & 0xffffu) | (other << 16);
        *(u32*)(hnext + (bg0 + n) * 1024 + j0 + mt * 4 + q) = packed;
      }
      // fused output projection partial: sum over this wave's 4 j's
      float p = h * wout;
      p += __shfl_xor(p, 16);
      p += __shfl_xor(p, 32);
      if (lane < 16) outred[mt * 16 + lane] = p;
    }
    __syncthreads();            // drains vmcnt: all h stores of this block issued
    if (tid < 16) {
      float o = outred[tid] + outred[16 + tid] + outred[32 + tid] + outred[48 + tid];
      atomicAdd(&out[(size_t)(bg0 + tid) * 512 + t], o);
    }
    if (tid == 0) {
      __threadfence();  // release side: write back L2 so h is LLC-visible
      __hip_atomic_fetch_add(ctr, 1u, __ATOMIC_RELEASE, __HIP_MEMORY_SCOPE_AGENT);
    }
  }
}

extern "C" void kernel_launch(void* const* d_in, const int* in_sizes, int n_in,
                              void* d_out, int out_size, void* d_ws, size_t ws_size,
                              hipStream_t stream) {
  const float* x    = (const float*)d_in[0];
  const float* W_ih = (const float*)d_in[1];
  const float* W_hh = (const float*)d_in[2];
  const float* b_ih = (const float*)d_in[3];
  const float* b_hh = (const float*)d_in[4];
  const float* Wout = (const float*)d_in[5];
  const float* bout = (const float*)d_in[6];
  float* out = (float*)d_out;

  unsigned char* ws = (unsigned char*)d_ws;
  u16* xT   = (u16*)(ws + WS_XT_OFF);
  u16* Wf   = (u16*)(ws + WS_WF_OFF);
  u16* hbuf = (u16*)(ws + WS_HB_OFF);
  u32* ctrs = (u32*)(ws + WS_CTR_OFF);

  k_init<<<128, 256, 0, stream>>>(hbuf, ctrs, out, bout);
  k_xpose<<<dim3(8, 8, 64), 256, 0, stream>>>(x, xT);
  k_wfrag<<<3072, 256, 0, stream>>>(W_ih, W_hh, Wf);

  void* args[8] = {&xT, &Wf, &hbuf, &ctrs, &b_ih, &b_hh, &Wout, &out};
  hipLaunchCooperativeKernel((const void*)k_lstm, dim3(256), dim3(512), args, 0, stream);
}

// Round 4
// 4646.254 us; speedup vs baseline: 5.0953x; 5.0953x over previous
//
#include <hip/hip_runtime.h>
#include <cstddef>

// SimpleLSTM: B=64, D=512, T=512, H=1024, O=1 — fp16, fence-free sync
// ws layout (~46.4 MB):
//   [0, 32MB)            xT: f16 [T=512][B=64][D=512]
//   [32MB, +12.58MB)     Wf: f16 A-frags [r=64][w=8][kl=6][mt=4][64][8]
//                        (reused after weight load as out-partials
//                         part[t=512][g=4][r=64][b16=16] f32 = 8MB)
//   [46,137,344, +256KB) h double buffer: f16 [2][B=64][H=1024]
//   [46,399,488, +2KB)   flags[4][64] u32 + ready counter @ +256
#define WS_XT_OFF   0ull
#define WS_WF_OFF   33554432ull
#define WS_HB_OFF   46137344ull
#define WS_CTR_OFF  46399488ull

typedef _Float16 f16x8 __attribute__((ext_vector_type(8)));
typedef float    f32x4 __attribute__((ext_vector_type(4)));
typedef unsigned short u16;
typedef unsigned int   u32;
typedef unsigned long long u64;

__device__ __forceinline__ u16 f2h(float f) {
  _Float16 h = (_Float16)f;                     // v_cvt_f16_f32, RNE
  return __builtin_bit_cast(u16, h);
}
__device__ __forceinline__ float sigm(float x) { return 1.0f / (1.0f + __expf(-x)); }

// ---------- K0: init h buf0 = 0, flags/ready = 0 ----------
__global__ __launch_bounds__(256) void k_init(u16* hbuf, u32* ctrs) {
  int t = blockIdx.x * 256 + threadIdx.x;       // 32768 threads
  ((u32*)hbuf)[t] = 0u;                         // zeroes buf0 (131072 B)
  if (t < 512) ctrs[t] = 0u;
}

// ---------- K1: x (B,D,T) f32 -> xT[t][b][d] f16 ----------
__global__ __launch_bounds__(256) void k_xpose(const float* __restrict__ x,
                                               u16* __restrict__ xT) {
  __shared__ float lds[64][65];
  const int d0 = blockIdx.x * 64, t0 = blockIdx.y * 64, b = blockIdx.z;
  const int tid = threadIdx.x;
  const int tt = tid & 63, dr = tid >> 6;
  const float* xp = x + ((size_t)b * 512 + d0) * 512 + t0 + tt;
#pragma unroll
  for (int i = 0; i < 16; ++i) {
    int dd = i * 4 + dr;
    lds[dd][tt] = xp[(size_t)dd * 512];
  }
  __syncthreads();
  const int dp = tid & 31, rr = tid >> 5;
#pragma unroll
  for (int i = 0; i < 8; ++i) {
    int tt2 = i * 8 + rr;
    u32 lo = f2h(lds[dp * 2][tt2]);
    u32 hi = f2h(lds[dp * 2 + 1][tt2]);
    *(u32*)(xT + ((size_t)(t0 + tt2) * 64 + b) * 512 + d0 + dp * 2) = lo | (hi << 16);
  }
}

// ---------- K2: pack [W_ih | W_hh] rows into per-lane MFMA A-fragments (f16) ----------
__global__ __launch_bounds__(256) void k_wfrag(const float* __restrict__ W_ih,
                                               const float* __restrict__ W_hh,
                                               u16* __restrict__ Wf) {
  int g = blockIdx.x * 256 + threadIdx.x;       // 786432 threads
  int lane = g & 63;
  int c  = g >> 6;
  int mt = c & 3;
  int c2 = c >> 2;
  int kl = c2 % 6;
  int c3 = c2 / 6;
  int wv = c3 & 7;
  int r  = c3 >> 3;
  int m = lane & 15, q = lane >> 4;
  int gate = m & 3;
  int j = r * 16 + mt * 4 + (m >> 2);
  int row = gate * 1024 + j;
  int ks = wv * 6 + kl;
  const float* src = (ks < 16) ? (W_ih + (size_t)row * 512 + ks * 32 + q * 8)
                               : (W_hh + (size_t)row * 1024 + (ks - 16) * 32 + q * 8);
  union { u16 s[8]; uint4 v; } U;
#pragma unroll
  for (int i = 0; i < 8; ++i) U.s[i] = f2h(src[i]);
  *(uint4*)(Wf + ((size_t)c * 64 + lane) * 8) = U.v;
}

// ---------- K3: persistent cooperative recurrence ----------
// grid 256 = 4 groups x 64 blocks; block 512 = 8 waves; 1 block/CU.
__global__ __launch_bounds__(512, 2) void k_lstm(
    const u16* __restrict__ xT, const u16* __restrict__ Wf,
    u16* hbuf, u32* ctrs,
    const float* __restrict__ b_ih, const float* __restrict__ b_hh,
    const float* __restrict__ W_out, float* __restrict__ part) {
  __shared__ float red[8 * 4 * 64 * 4];   // [wave][mt][lane][4] partial accs, 32 KB
  __shared__ float outred[64];            // [mt][16b]
  const int tid = threadIdx.x;
  const int w = tid >> 6, lane = tid & 63;
  const int blk = blockIdx.x, g = blk >> 6, r = blk & 63;
  const int bg0 = g * 16, j0 = r * 16;
  const int n = lane & 15, q = lane >> 4;

  // Step-invariant weights -> registers
  f16x8 wfr[6][4];
#pragma unroll
  for (int kl = 0; kl < 6; ++kl)
#pragma unroll
    for (int mt = 0; mt < 4; ++mt) {
      size_t c = ((size_t)(r * 8 + w) * 6 + kl) * 4 + mt;
      wfr[kl][mt] = *(const f16x8*)(Wf + (c * 64 + lane) * 8);
    }

  float bias0 = 0.f, bias1 = 0.f, bias2 = 0.f, bias3 = 0.f, wout = 0.f;
  if (w < 4) {
    int j = j0 + w * 4 + q;
    bias0 = b_ih[j]        + b_hh[j];
    bias1 = b_ih[1024 + j] + b_hh[1024 + j];
    bias2 = b_ih[2048 + j] + b_hh[2048 + j];
    bias3 = b_ih[3072 + j] + b_hh[3072 + j];
    wout  = W_out[j];
  }

  u32* flags = ctrs;                      // [g*64 + r], holds completed-step count
  u32* ready = ctrs + 256;

  // One-time grid barrier: all Wf loads done before part[] overwrites Wf
  __syncthreads();                        // each wave drains vmcnt -> wfr in regs
  if (tid == 0) {
    __hip_atomic_fetch_add(ready, 1u, __ATOMIC_RELAXED, __HIP_MEMORY_SCOPE_AGENT);
    while (__hip_atomic_load(ready, __ATOMIC_RELAXED, __HIP_MEMORY_SCOPE_AGENT) < 256u)
      __builtin_amdgcn_s_sleep(8);
  }
  __syncthreads();
  asm volatile("" ::: "memory");

  u16* hb0 = hbuf;
  u16* hb1 = hbuf + 64 * 1024;
  float c_state = 0.f;
  const f32x4 zero = {0.f, 0.f, 0.f, 0.f};

  for (int t = 0; t < 512; ++t) {
    // waves holding h k-steps wait until all 64 group blocks finished step t-1
    if (w >= 2 && t > 0) {
      u32 f = __hip_atomic_load(&flags[g * 64 + lane], __ATOMIC_RELAXED,
                                __HIP_MEMORY_SCOPE_AGENT);
      while (!__all((int)(f >= (u32)t))) {
        __builtin_amdgcn_s_sleep(1);
        f = __hip_atomic_load(&flags[g * 64 + lane], __ATOMIC_RELAXED,
                              __HIP_MEMORY_SCOPE_AGENT);
      }
    }
    asm volatile("" ::: "memory");   // no hoisting of h loads above the spin

    const u16* hcur = (t & 1) ? hb1 : hb0;
    u16* hnext      = (t & 1) ? hb0 : hb1;
    const u16* xtb  = xT + (size_t)t * 32768;

    // B-fragments: [x_t ; h_t] for this wave's 6 k-steps
    f16x8 bfr[6];
#pragma unroll
    for (int kl = 0; kl < 6; ++kl) {
      int ks = w * 6 + kl;
      if (ks < 16) {
        bfr[kl] = *(const f16x8*)(xtb + (bg0 + n) * 512 + ks * 32 + q * 8);
      } else {
        const u64* p = (const u64*)(hcur + (bg0 + n) * 1024 + (ks - 16) * 32 + q * 8);
        union { u64 u[2]; f16x8 v; } U;
        U.u[0] = __hip_atomic_load(p,     __ATOMIC_RELAXED, __HIP_MEMORY_SCOPE_AGENT);
        U.u[1] = __hip_atomic_load(p + 1, __ATOMIC_RELAXED, __HIP_MEMORY_SCOPE_AGENT);
        bfr[kl] = U.v;
      }
    }

    f32x4 acc[4];
#pragma unroll
    for (int mt = 0; mt < 4; ++mt) acc[mt] = zero;
#pragma unroll
    for (int kl = 0; kl < 6; ++kl)
#pragma unroll
      for (int mt = 0; mt < 4; ++mt)
        acc[mt] = __builtin_amdgcn_mfma_f32_16x16x32_f16(wfr[kl][mt], bfr[kl], acc[mt], 0, 0, 0);

#pragma unroll
    for (int mt = 0; mt < 4; ++mt)
      *(f32x4*)&red[((w * 4 + mt) * 64 + lane) * 4] = acc[mt];
    __syncthreads();

    if (w < 4) {
      const int mt = w;
      f32x4 s = zero;
#pragma unroll
      for (int wv = 0; wv < 8; ++wv)
        s += *(const f32x4*)&red[((wv * 4 + mt) * 64 + lane) * 4];
      // lane owns all 4 gates of (b = bg0+n, j = j0+mt*4+q): regs = i,f,g,o
      float gi = s.x + bias0, gf = s.y + bias1, gg = s.z + bias2, go = s.w + bias3;
      c_state = sigm(gf) * c_state + sigm(gi) * tanhf(gg);
      float h = sigm(go) * tanhf(c_state);
      // pack f16 pairs across quads, LLC-direct store to hnext[b][j]
      u32 hv = (u32)__builtin_bit_cast(u16, (_Float16)h);
      u32 other = (u32)__shfl_xor((int)hv, 16);
      if ((q & 1) == 0) {
        u32 packed = (hv & 0xffffu) | (other << 16);
        __hip_atomic_store((u32*)(hnext + (bg0 + n) * 1024 + j0 + mt * 4 + q), packed,
                           __ATOMIC_RELAXED, __HIP_MEMORY_SCOPE_AGENT);
      }
      // fused output projection partial over this wave's 4 j's
      float p = h * wout;
      p += __shfl_xor(p, 16);
      p += __shfl_xor(p, 32);
      if (lane < 16) outred[mt * 16 + lane] = p;
    }
    __syncthreads();            // drains vmcnt: h stores of this block at LLC
    if (tid < 16) {
      float o = outred[tid] + outred[16 + tid] + outred[32 + tid] + outred[48 + tid];
      part[((size_t)(t * 4 + g) * 64 + r) * 16 + tid] = o;   // plain store
    }
    if (tid == 0)
      __hip_atomic_store(&flags[g * 64 + r], (u32)(t + 1),
                         __ATOMIC_RELAXED, __HIP_MEMORY_SCOPE_AGENT);
  }
}

// ---------- K4: out[b][t] = b_out + sum_r part[t][g][r][b&15] ----------
__global__ __launch_bounds__(256) void k_out(const float* __restrict__ part,
                                             const float* __restrict__ b_out,
                                             float* __restrict__ out) {
  int gi = blockIdx.x * 256 + threadIdx.x;      // 32768 threads
  int t = gi >> 6, b = gi & 63, g = b >> 4, b16 = b & 15;
  const float* p = part + ((size_t)(t * 4 + g) * 64) * 16 + b16;
  float s = b_out[0];
#pragma unroll 8
  for (int r = 0; r < 64; ++r) s += p[r * 16];
  out[(size_t)b * 512 + t] = s;
}

extern "C" void kernel_launch(void* const* d_in, const int* in_sizes, int n_in,
                              void* d_out, int out_size, void* d_ws, size_t ws_size,
                              hipStream_t stream) {
  const float* x    = (const float*)d_in[0];
  const float* W_ih = (const float*)d_in[1];
  const float* W_hh = (const float*)d_in[2];
  const float* b_ih = (const float*)d_in[3];
  const float* b_hh = (const float*)d_in[4];
  const float* Wout = (const float*)d_in[5];
  const float* bout = (const float*)d_in[6];
  float* out = (float*)d_out;

  unsigned char* ws = (unsigned char*)d_ws;
  u16* xT   = (u16*)(ws + WS_XT_OFF);
  u16* Wf   = (u16*)(ws + WS_WF_OFF);
  u16* hbuf = (u16*)(ws + WS_HB_OFF);
  u32* ctrs = (u32*)(ws + WS_CTR_OFF);
  float* part = (float*)(ws + WS_WF_OFF);       // reuses Wf region after load

  k_init<<<128, 256, 0, stream>>>(hbuf, ctrs);
  k_xpose<<<dim3(8, 8, 64), 256, 0, stream>>>(x, xT);
  k_wfrag<<<3072, 256, 0, stream>>>(W_ih, W_hh, Wf);

  void* args[8] = {&xT, &Wf, &hbuf, &ctrs, &b_ih, &b_hh, &Wout, &part};
  hipLaunchCooperativeKernel((const void*)k_lstm, dim3(256), dim3(512), args, 0, stream);

  k_out<<<128, 256, 0, stream>>>(part, bout, out);
}

// Round 5
// 2961.305 us; speedup vs baseline: 7.9944x; 1.5690x over previous
//
#include <hip/hip_runtime.h>
#include <cstddef>

// SimpleLSTM: B=64, D=512, T=512, H=1024, O=1 — fp16, fine-grained flag sync
// ws layout (~46.4 MB):
//   [0, 32MB)            xT: f16 [T=512][B=64][D=512]
//   [32MB, +12.58MB)     Wf: f16 A-frags [r=64][w=8][kl=6][mt=4][64][8]
//                        (reused after weight load as out-partials
//                         part[t=512][g=4][r=64][b16=16] f32 = 8MB)
//   [46,137,344, +256KB) h double buffer: f16 [2][B=64][H=1024]
//   [46,399,488, +2KB)   flags[4][64] u32 + ready counter @ +256
#define WS_XT_OFF   0ull
#define WS_WF_OFF   33554432ull
#define WS_HB_OFF   46137344ull
#define WS_CTR_OFF  46399488ull

typedef _Float16 f16x8 __attribute__((ext_vector_type(8)));
typedef float    f32x4 __attribute__((ext_vector_type(4)));
typedef unsigned short u16;
typedef unsigned int   u32;
typedef unsigned long long u64;

__device__ __forceinline__ u16 f2h(float f) {
  _Float16 h = (_Float16)f;                     // v_cvt_f16_f32, RNE
  return __builtin_bit_cast(u16, h);
}
__device__ __forceinline__ float sigm(float x) { return 1.0f / (1.0f + __expf(-x)); }

// ---------- K0: init h buf0 = 0, flags/ready = 0 ----------
__global__ __launch_bounds__(256) void k_init(u16* hbuf, u32* ctrs) {
  int t = blockIdx.x * 256 + threadIdx.x;       // 32768 threads
  ((u32*)hbuf)[t] = 0u;                         // zeroes buf0 (131072 B)
  if (t < 512) ctrs[t] = 0u;
}

// ---------- K1: x (B,D,T) f32 -> xT[t][b][d] f16 ----------
__global__ __launch_bounds__(256) void k_xpose(const float* __restrict__ x,
                                               u16* __restrict__ xT) {
  __shared__ float lds[64][65];
  const int d0 = blockIdx.x * 64, t0 = blockIdx.y * 64, b = blockIdx.z;
  const int tid = threadIdx.x;
  const int tt = tid & 63, dr = tid >> 6;
  const float* xp = x + ((size_t)b * 512 + d0) * 512 + t0 + tt;
#pragma unroll
  for (int i = 0; i < 16; ++i) {
    int dd = i * 4 + dr;
    lds[dd][tt] = xp[(size_t)dd * 512];
  }
  __syncthreads();
  const int dp = tid & 31, rr = tid >> 5;
#pragma unroll
  for (int i = 0; i < 8; ++i) {
    int tt2 = i * 8 + rr;
    u32 lo = f2h(lds[dp * 2][tt2]);
    u32 hi = f2h(lds[dp * 2 + 1][tt2]);
    *(u32*)(xT + ((size_t)(t0 + tt2) * 64 + b) * 512 + d0 + dp * 2) = lo | (hi << 16);
  }
}

// ---------- K2: pack [W_ih | W_hh] rows into per-lane MFMA A-fragments (f16) ----------
__global__ __launch_bounds__(256) void k_wfrag(const float* __restrict__ W_ih,
                                               const float* __restrict__ W_hh,
                                               u16* __restrict__ Wf) {
  int g = blockIdx.x * 256 + threadIdx.x;       // 786432 threads
  int lane = g & 63;
  int c  = g >> 6;
  int mt = c & 3;
  int c2 = c >> 2;
  int kl = c2 % 6;
  int c3 = c2 / 6;
  int wv = c3 & 7;
  int r  = c3 >> 3;
  int m = lane & 15, q = lane >> 4;
  int gate = m & 3;
  int j = r * 16 + mt * 4 + (m >> 2);
  int row = gate * 1024 + j;
  int ks = wv * 6 + kl;
  const float* src = (ks < 16) ? (W_ih + (size_t)row * 512 + ks * 32 + q * 8)
                               : (W_hh + (size_t)row * 1024 + (ks - 16) * 32 + q * 8);
  union { u16 s[8]; uint4 v; } U;
#pragma unroll
  for (int i = 0; i < 8; ++i) U.s[i] = f2h(src[i]);
  *(uint4*)(Wf + ((size_t)c * 64 + lane) * 8) = U.v;
}

// ---------- K3: persistent cooperative recurrence ----------
// grid 256 = 4 groups x 64 blocks; block 512 = 8 waves; 1 block/CU.
// Wave w consumes h rows j in [32*max(0,6w-16), 32*(6w-10)), i.e. producer
// blocks r' in [rlo, rhi) with rlo=2*max(0,6w-16), rhi=12w-20. Ranges are
// disjoint across w=2..7 and union to [0,64): each flag has ONE poller per
// consumer block, and collectively a block observes all 64 producers before
// its first h-write of the step (double-buffer overwrite guard).
__global__ __launch_bounds__(512, 2) void k_lstm(
    const u16* __restrict__ xT, const u16* __restrict__ Wf,
    u16* hbuf, u32* ctrs,
    const float* __restrict__ b_ih, const float* __restrict__ b_hh,
    const float* __restrict__ W_out, float* __restrict__ part) {
  __shared__ float red[8 * 4 * 64 * 4];   // [wave][mt][lane][4] partial accs, 32 KB
  __shared__ float outred[64];            // [mt][16b]
  const int tid = threadIdx.x;
  const int w = tid >> 6, lane = tid & 63;
  const int blk = blockIdx.x, g = blk >> 6, r = blk & 63;
  const int bg0 = g * 16, j0 = r * 16;
  const int n = lane & 15, q = lane >> 4;

  // Step-invariant weights -> registers
  f16x8 wfr[6][4];
#pragma unroll
  for (int kl = 0; kl < 6; ++kl)
#pragma unroll
    for (int mt = 0; mt < 4; ++mt) {
      size_t c = ((size_t)(r * 8 + w) * 6 + kl) * 4 + mt;
      wfr[kl][mt] = *(const f16x8*)(Wf + (c * 64 + lane) * 8);
    }

  float bias0 = 0.f, bias1 = 0.f, bias2 = 0.f, bias3 = 0.f, wout = 0.f;
  if (w < 4) {
    int j = j0 + w * 4 + q;
    bias0 = b_ih[j]        + b_hh[j];
    bias1 = b_ih[1024 + j] + b_hh[1024 + j];
    bias2 = b_ih[2048 + j] + b_hh[2048 + j];
    bias3 = b_ih[3072 + j] + b_hh[3072 + j];
    wout  = W_out[j];
  }

  u32* flags = ctrs;                      // [g*64 + r], holds completed-step count
  u32* ready = ctrs + 256;

  // Per-wave poll pointer: disjoint producer range [rlo, rhi)
  const int klo = (6 * w - 16) > 0 ? (6 * w - 16) : 0;
  const int rlo = 2 * klo;
  const int cnt = (12 * w - 20) - rlo;    // 4 for w=2, 12 for w=3..7
  const u32* fp = &flags[g * 64 + rlo + ((w >= 2 && lane < cnt) ? lane : 0)];

  // One-time grid barrier: all Wf loads done before part[] overwrites Wf
  __syncthreads();                        // each wave drains vmcnt -> wfr in regs
  if (tid == 0) {
    __hip_atomic_fetch_add(ready, 1u, __ATOMIC_RELAXED, __HIP_MEMORY_SCOPE_AGENT);
    while (__hip_atomic_load(ready, __ATOMIC_RELAXED, __HIP_MEMORY_SCOPE_AGENT) < 256u)
      __builtin_amdgcn_s_sleep(8);
  }
  __syncthreads();
  asm volatile("" ::: "memory");

  u16* hb0 = hbuf;
  u16* hb1 = hbuf + 64 * 1024;
  float c_state = 0.f;
  const f32x4 zero = {0.f, 0.f, 0.f, 0.f};

  for (int t = 0; t < 512; ++t) {
    // wait only for THIS wave's producer blocks to finish step t-1
    if (w >= 2 && t > 0) {
      u32 f = __hip_atomic_load(fp, __ATOMIC_RELAXED, __HIP_MEMORY_SCOPE_AGENT);
      while (!__all((int)(f >= (u32)t))) {
        __builtin_amdgcn_s_sleep(1);
        f = __hip_atomic_load(fp, __ATOMIC_RELAXED, __HIP_MEMORY_SCOPE_AGENT);
      }
    }
    asm volatile("" ::: "memory");   // no hoisting of h loads above the spin

    const u16* hcur = (t & 1) ? hb1 : hb0;
    u16* hnext      = (t & 1) ? hb0 : hb1;
    const u16* xtb  = xT + (size_t)t * 32768;

    // B-fragments: [x_t ; h_t] for this wave's 6 k-steps
    f16x8 bfr[6];
#pragma unroll
    for (int kl = 0; kl < 6; ++kl) {
      int ks = w * 6 + kl;
      if (ks < 16) {
        bfr[kl] = *(const f16x8*)(xtb + (bg0 + n) * 512 + ks * 32 + q * 8);
      } else {
        const u64* p = (const u64*)(hcur + (bg0 + n) * 1024 + (ks - 16) * 32 + q * 8);
        union { u64 u[2]; f16x8 v; } U;
        U.u[0] = __hip_atomic_load(p,     __ATOMIC_RELAXED, __HIP_MEMORY_SCOPE_AGENT);
        U.u[1] = __hip_atomic_load(p + 1, __ATOMIC_RELAXED, __HIP_MEMORY_SCOPE_AGENT);
        bfr[kl] = U.v;
      }
    }

    f32x4 acc[4];
#pragma unroll
    for (int mt = 0; mt < 4; ++mt) acc[mt] = zero;
#pragma unroll
    for (int kl = 0; kl < 6; ++kl)
#pragma unroll
      for (int mt = 0; mt < 4; ++mt)
        acc[mt] = __builtin_amdgcn_mfma_f32_16x16x32_f16(wfr[kl][mt], bfr[kl], acc[mt], 0, 0, 0);

#pragma unroll
    for (int mt = 0; mt < 4; ++mt)
      *(f32x4*)&red[((w * 4 + mt) * 64 + lane) * 4] = acc[mt];
    __syncthreads();

    if (w < 4) {
      const int mt = w;
      f32x4 s = zero;
#pragma unroll
      for (int wv = 0; wv < 8; ++wv)
        s += *(const f32x4*)&red[((wv * 4 + mt) * 64 + lane) * 4];
      // lane owns all 4 gates of (b = bg0+n, j = j0+mt*4+q): regs = i,f,g,o
      float gi = s.x + bias0, gf = s.y + bias1, gg = s.z + bias2, go = s.w + bias3;
      c_state = sigm(gf) * c_state + sigm(gi) * tanhf(gg);
      float h = sigm(go) * tanhf(c_state);
      // pack f16 pairs across quads, LLC-direct store to hnext[b][j]
      u32 hv = (u32)__builtin_bit_cast(u16, (_Float16)h);
      u32 other = (u32)__shfl_xor((int)hv, 16);
      if ((q & 1) == 0) {
        u32 packed = (hv & 0xffffu) | (other << 16);
        __hip_atomic_store((u32*)(hnext + (bg0 + n) * 1024 + j0 + mt * 4 + q), packed,
                           __ATOMIC_RELAXED, __HIP_MEMORY_SCOPE_AGENT);
      }
      // fused output projection partial over this wave's 4 j's
      float p = h * wout;
      p += __shfl_xor(p, 16);
      p += __shfl_xor(p, 32);
      if (lane < 16) outred[mt * 16 + lane] = p;
    }
    __syncthreads();            // drains vmcnt: h stores of this block at LLC
    if (tid < 16) {
      float o = outred[tid] + outred[16 + tid] + outred[32 + tid] + outred[48 + tid];
      part[((size_t)(t * 4 + g) * 64 + r) * 16 + tid] = o;   // plain store
    }
    if (tid == 0)
      __hip_atomic_store(&flags[g * 64 + r], (u32)(t + 1),
                         __ATOMIC_RELAXED, __HIP_MEMORY_SCOPE_AGENT);
  }
}

// ---------- K4: out[b][t] = b_out + sum_r part[t][g][r][b&15] ----------
__global__ __launch_bounds__(256) void k_out(const float* __restrict__ part,
                                             const float* __restrict__ b_out,
                                             float* __restrict__ out) {
  int gi = blockIdx.x * 256 + threadIdx.x;      // 32768 threads
  int t = gi >> 6, b = gi & 63, g = b >> 4, b16 = b & 15;
  const float* p = part + ((size_t)(t * 4 + g) * 64) * 16 + b16;
  float s = b_out[0];
#pragma unroll 8
  for (int r = 0; r < 64; ++r) s += p[r * 16];
  out[(size_t)b * 512 + t] = s;
}

extern "C" void kernel_launch(void* const* d_in, const int* in_sizes, int n_in,
                              void* d_out, int out_size, void* d_ws, size_t ws_size,
                              hipStream_t stream) {
  const float* x    = (const float*)d_in[0];
  const float* W_ih = (const float*)d_in[1];
  const float* W_hh = (const float*)d_in[2];
  const float* b_ih = (const float*)d_in[3];
  const float* b_hh = (const float*)d_in[4];
  const float* Wout = (const float*)d_in[5];
  const float* bout = (const float*)d_in[6];
  float* out = (float*)d_out;

  unsigned char* ws = (unsigned char*)d_ws;
  u16* xT   = (u16*)(ws + WS_XT_OFF);
  u16* Wf   = (u16*)(ws + WS_WF_OFF);
  u16* hbuf = (u16*)(ws + WS_HB_OFF);
  u32* ctrs = (u32*)(ws + WS_CTR_OFF);
  float* part = (float*)(ws + WS_WF_OFF);       // reuses Wf region after load

  k_init<<<128, 256, 0, stream>>>(hbuf, ctrs);
  k_xpose<<<dim3(8, 8, 64), 256, 0, stream>>>(x, xT);
  k_wfrag<<<3072, 256, 0, stream>>>(W_ih, W_hh, Wf);

  void* args[8] = {&xT, &Wf, &hbuf, &ctrs, &b_ih, &b_hh, &Wout, &part};
  hipLaunchCooperativeKernel((const void*)k_lstm, dim3(256), dim3(512), args, 0, stream);

  k_out<<<128, 256, 0, stream>>>(part, bout, out);
}

// Round 6
// 2596.901 us; speedup vs baseline: 9.1162x; 1.1403x over previous
//
#include <hip/hip_runtime.h>
#include <cstddef>

// SimpleLSTM: B=64, D=512, T=512, H=1024, O=1 — fp16, padded subflags, 1 barrier/step
// ws layout (~46.53 MB):
//   [0, 32MB)            xT: f16 [T=512][B=64][D=512]
//   [32MB, +12.58MB)     Wf: f16 A-frags [r=64][ks=48][mt=4][lane=64][8]
//                        (reused after weight load as out-partials
//                         part[t=512][g=4][r=64][b16=16] f32 = 8MB, atomicAdd'd)
//   [46,137,344, +256KB) h double buffer: f16 [2][B=64][H=1024]
//   [46,399,488, +128KB) subflags[g=4][r=64][mt=4] u32, stride 32 u32 (128B/flag)
//                        + ready counter at index 32768
#define WS_XT_OFF   0ull
#define WS_WF_OFF   33554432ull
#define WS_HB_OFF   46137344ull
#define WS_CTR_OFF  46399488ull

typedef _Float16 f16x8 __attribute__((ext_vector_type(8)));
typedef float    f32x4 __attribute__((ext_vector_type(4)));
typedef unsigned short u16;
typedef unsigned int   u32;
typedef unsigned long long u64;

__device__ __forceinline__ u16 f2h(float f) {
  _Float16 h = (_Float16)f;                     // v_cvt_f16_f32, RNE
  return __builtin_bit_cast(u16, h);
}
__device__ __forceinline__ float sigm(float x) { return 1.0f / (1.0f + __expf(-x)); }

// ---------- K0: init h buf0 = 0, subflags/ready = 0 ----------
__global__ __launch_bounds__(256) void k_init(u16* hbuf, u32* ctrs) {
  int t = blockIdx.x * 256 + threadIdx.x;       // 32768 threads
  ((u32*)hbuf)[t] = 0u;                         // zeroes buf0 (131072 B)
  ctrs[t] = 0u;                                 // 32768 u32 = all subflags
  if (t == 0) ctrs[32768] = 0u;                 // ready counter
}

// ---------- K1: x (B,D,T) f32 -> xT[t][b][d] f16 ----------
__global__ __launch_bounds__(256) void k_xpose(const float* __restrict__ x,
                                               u16* __restrict__ xT) {
  __shared__ float lds[64][65];
  const int d0 = blockIdx.x * 64, t0 = blockIdx.y * 64, b = blockIdx.z;
  const int tid = threadIdx.x;
  const int tt = tid & 63, dr = tid >> 6;
  const float* xp = x + ((size_t)b * 512 + d0) * 512 + t0 + tt;
#pragma unroll
  for (int i = 0; i < 16; ++i) {
    int dd = i * 4 + dr;
    lds[dd][tt] = xp[(size_t)dd * 512];
  }
  __syncthreads();
  const int dp = tid & 31, rr = tid >> 5;
#pragma unroll
  for (int i = 0; i < 8; ++i) {
    int tt2 = i * 8 + rr;
    u32 lo = f2h(lds[dp * 2][tt2]);
    u32 hi = f2h(lds[dp * 2 + 1][tt2]);
    *(u32*)(xT + ((size_t)(t0 + tt2) * 64 + b) * 512 + d0 + dp * 2) = lo | (hi << 16);
  }
}

// ---------- K2: pack [W_ih | W_hh] rows into per-lane MFMA A-fragments (f16) ----------
// chunk c = (r*48 + ks)*4 + mt ; within-tile row m: gate=m&3, j=r*16+mt*4+(m>>2)
__global__ __launch_bounds__(256) void k_wfrag(const float* __restrict__ W_ih,
                                               const float* __restrict__ W_hh,
                                               u16* __restrict__ Wf) {
  int g = blockIdx.x * 256 + threadIdx.x;       // 786432 threads
  int lane = g & 63;
  int c  = g >> 6;                              // [0, 12288)
  int mt = c & 3;
  int cc = c >> 2;
  int ks = cc % 48;
  int r  = cc / 48;
  int m = lane & 15, q = lane >> 4;
  int gate = m & 3;
  int j = r * 16 + mt * 4 + (m >> 2);
  int row = gate * 1024 + j;
  const float* src = (ks < 16) ? (W_ih + (size_t)row * 512 + ks * 32 + q * 8)
                               : (W_hh + (size_t)row * 1024 + (ks - 16) * 32 + q * 8);
  union { u16 s[8]; uint4 v; } U;
#pragma unroll
  for (int i = 0; i < 8; ++i) U.s[i] = f2h(src[i]);
  *(uint4*)(Wf + ((size_t)c * 64 + lane) * 8) = U.v;
}

// ---------- K3: persistent cooperative recurrence ----------
// grid 256 = 4 groups x 64 blocks; block 512 = 8 waves; 1 block/CU.
// Wave w handles k-steps ks = {2w, 2w+1} (x) and {16+4w .. 16+4w+3} (h).
// Its h rows j in [128w, 128w+128) come from producer blocks r' in [8w, 8w+8)
// — disjoint across w, union = [0,64). Every wave polls its own 8 blocks x 4
// mt subflags (one per 128B line, 64 pollers/line). All h-writes happen after
// barrier 1, which requires all waves' spins passed => all 64x4 subflags >= t
// => every block consumed its step t-1 reads (reads precede its barrier 1).
__global__ __launch_bounds__(512, 2) void k_lstm(
    const u16* __restrict__ xT, const u16* __restrict__ Wf,
    u16* hbuf, u32* ctrs,
    const float* __restrict__ b_ih, const float* __restrict__ b_hh,
    const float* __restrict__ W_out, float* __restrict__ part) {
  __shared__ f32x4 red[2][8 * 4 * 64];    // [parity][wave][mt][lane], 64 KB
  const int tid = threadIdx.x;
  const int w = tid >> 6, lane = tid & 63;
  const int blk = blockIdx.x, g = blk >> 6, r = blk & 63;
  const int bg0 = g * 16, j0 = r * 16;
  const int n = lane & 15, q = lane >> 4;

  // Step-invariant weights -> registers (AGPR-eligible on gfx950)
  f16x8 wfr[6][4];
#pragma unroll
  for (int kl = 0; kl < 6; ++kl) {
    int ks = (kl < 2) ? (2 * w + kl) : (16 + 4 * w + (kl - 2));
#pragma unroll
    for (int mt = 0; mt < 4; ++mt) {
      size_t c = ((size_t)r * 48 + ks) * 4 + mt;
      wfr[kl][mt] = *(const f16x8*)(Wf + (c * 64 + lane) * 8);
    }
  }

  float bias0 = 0.f, bias1 = 0.f, bias2 = 0.f, bias3 = 0.f, wout = 0.f;
  if (w < 4) {
    int j = j0 + w * 4 + q;
    bias0 = b_ih[j]        + b_hh[j];
    bias1 = b_ih[1024 + j] + b_hh[1024 + j];
    bias2 = b_ih[2048 + j] + b_hh[2048 + j];
    bias3 = b_ih[3072 + j] + b_hh[3072 + j];
    wout  = W_out[j];
  }

  u32* ready = ctrs + 32768;
  // subflag(g,r,mt) at ctrs[((g*64+r)*4+mt)*32] — one per 128B line
  u32* sf = ctrs + ((((u32)g * 64 + r) * 4 + (u32)w) << 5);     // used by w<4
  // poll pointer: lane<32 -> producer block 8w+(lane>>2), mt=lane&3
  const u32* fp = ctrs + ((((u32)g * 64 + (8 * w + (lane >> 2))) * 4 + (lane & 3)) << 5);

  // One-time grid barrier: all Wf loads done before part[] overwrites Wf
  __syncthreads();                        // each wave drains vmcnt -> wfr in regs
  if (tid == 0) {
    __hip_atomic_fetch_add(ready, 1u, __ATOMIC_RELAXED, __HIP_MEMORY_SCOPE_AGENT);
    while (__hip_atomic_load(ready, __ATOMIC_RELAXED, __HIP_MEMORY_SCOPE_AGENT) < 256u)
      __builtin_amdgcn_s_sleep(8);
  }
  __syncthreads();
  // zero own out-partial slice part[t=tid][g][r][0..16) (plain stores -> own L2)
  {
    f32x4 z = {0.f, 0.f, 0.f, 0.f};
    f32x4* p4 = (f32x4*)&part[((size_t)(tid * 4 + g) * 64 + r) * 16];
    p4[0] = z; p4[1] = z; p4[2] = z; p4[3] = z;
  }
  __syncthreads();                        // drain zero stores before any atomicAdd
  asm volatile("" ::: "memory");

  u16* hb0 = hbuf;
  u16* hb1 = hbuf + 64 * 1024;
  float c_state = 0.f;
  const f32x4 zero = {0.f, 0.f, 0.f, 0.f};

  for (int t = 0; t < 512; ++t) {
    const u16* hcur = (t & 1) ? hb1 : hb0;
    u16* hnext      = (t & 1) ? hb0 : hb1;
    const u16* xtb  = xT + (size_t)t * 32768;

    // flag-independent x loads first (ks = 2w, 2w+1)
    f16x8 bfr[6];
#pragma unroll
    for (int kl = 0; kl < 2; ++kl)
      bfr[kl] = *(const f16x8*)(xtb + (bg0 + n) * 512 + (2 * w + kl) * 32 + q * 8);

    // busy-poll own producer subflags (no sleep; throttled by load RTT)
    if (t > 0) {
      for (;;) {
        u32 f = 0xffffffffu;
        if (lane < 32)
          f = __hip_atomic_load(fp, __ATOMIC_RELAXED, __HIP_MEMORY_SCOPE_AGENT);
        if (__all((int)(f >= (u32)t))) break;
      }
    }
    asm volatile("" ::: "memory");   // no hoisting of h loads above the spin

    // h loads immediately after spin exit (ks-16 = 4w .. 4w+3)
#pragma unroll
    for (int kl = 2; kl < 6; ++kl) {
      const u64* p = (const u64*)(hcur + (bg0 + n) * 1024 + (4 * w + kl - 2) * 32 + q * 8);
      union { u64 u[2]; f16x8 v; } U;
      U.u[0] = __hip_atomic_load(p,     __ATOMIC_RELAXED, __HIP_MEMORY_SCOPE_AGENT);
      U.u[1] = __hip_atomic_load(p + 1, __ATOMIC_RELAXED, __HIP_MEMORY_SCOPE_AGENT);
      bfr[kl] = U.v;
    }

    f32x4 acc[4];
#pragma unroll
    for (int mt = 0; mt < 4; ++mt)
      acc[mt] = __builtin_amdgcn_mfma_f32_16x16x32_f16(wfr[0][mt], bfr[0], zero, 0, 0, 0);
#pragma unroll
    for (int kl = 1; kl < 6; ++kl)
#pragma unroll
      for (int mt = 0; mt < 4; ++mt)
        acc[mt] = __builtin_amdgcn_mfma_f32_16x16x32_f16(wfr[kl][mt], bfr[kl], acc[mt], 0, 0, 0);

#pragma unroll
    for (int mt = 0; mt < 4; ++mt)
      red[t & 1][(w * 4 + mt) * 64 + lane] = acc[mt];
    __syncthreads();                      // the ONLY barrier per step

    if (w < 4) {
      const int mt = w;
      f32x4 s = zero;
#pragma unroll
      for (int wv = 0; wv < 8; ++wv)
        s += red[t & 1][(wv * 4 + mt) * 64 + lane];
      // lane owns all 4 gates of (b = bg0+n, j = j0+mt*4+q): regs = i,f,g,o
      float gi = s.x + bias0, gf = s.y + bias1, gg = s.z + bias2, go = s.w + bias3;
      c_state = sigm(gf) * c_state + sigm(gi) * tanhf(gg);
      float h = sigm(go) * tanhf(c_state);
      // pack f16 pairs across quads, LLC-direct store to hnext[b][j]
      u32 hv = (u32)__builtin_bit_cast(u16, (_Float16)h);
      u32 other = (u32)__shfl_xor((int)hv, 16);
      if ((q & 1) == 0) {
        u32 packed = (hv & 0xffffu) | (other << 16);
        __hip_atomic_store((u32*)(hnext + (bg0 + n) * 1024 + j0 + mt * 4 + q), packed,
                           __ATOMIC_RELAXED, __HIP_MEMORY_SCOPE_AGENT);
      }
      // drain own h stores to LLC, then release this wave's subflag ASAP
      asm volatile("s_waitcnt vmcnt(0)" ::: "memory");
      if (lane == 0)
        __hip_atomic_store(sf, (u32)(t + 1), __ATOMIC_RELAXED, __HIP_MEMORY_SCOPE_AGENT);
      // fused out-projection partial (fire-and-forget, own-L2 atomic)
      float p = h * wout;
      p += __shfl_xor(p, 16);
      p += __shfl_xor(p, 32);
      if (lane < 16)
        __hip_atomic_fetch_add(&part[((size_t)(t * 4 + g) * 64 + r) * 16 + lane], p,
                               __ATOMIC_RELAXED, __HIP_MEMORY_SCOPE_WORKGROUP);
    }
  }
}

// ---------- K4: out[b][t] = b_out + sum_r part[t][g][r][b&15] ----------
__global__ __launch_bounds__(256) void k_out(const float* __restrict__ part,
                                             const float* __restrict__ b_out,
                                             float* __restrict__ out) {
  int gi = blockIdx.x * 256 + threadIdx.x;      // 32768 threads
  int t = gi >> 6, b = gi & 63, g = b >> 4, b16 = b & 15;
  const float* p = part + ((size_t)(t * 4 + g) * 64) * 16 + b16;
  float s = b_out[0];
#pragma unroll 8
  for (int r = 0; r < 64; ++r) s += p[r * 16];
  out[(size_t)b * 512 + t] = s;
}

extern "C" void kernel_launch(void* const* d_in, const int* in_sizes, int n_in,
                              void* d_out, int out_size, void* d_ws, size_t ws_size,
                              hipStream_t stream) {
  const float* x    = (const float*)d_in[0];
  const float* W_ih = (const float*)d_in[1];
  const float* W_hh = (const float*)d_in[2];
  const float* b_ih = (const float*)d_in[3];
  const float* b_hh = (const float*)d_in[4];
  const float* Wout = (const float*)d_in[5];
  const float* bout = (const float*)d_in[6];
  float* out = (float*)d_out;

  unsigned char* ws = (unsigned char*)d_ws;
  u16* xT   = (u16*)(ws + WS_XT_OFF);
  u16* Wf   = (u16*)(ws + WS_WF_OFF);
  u16* hbuf = (u16*)(ws + WS_HB_OFF);
  u32* ctrs = (u32*)(ws + WS_CTR_OFF);
  float* part = (float*)(ws + WS_WF_OFF);       // reuses Wf region after load

  k_init<<<128, 256, 0, stream>>>(hbuf, ctrs);
  k_xpose<<<dim3(8, 8, 64), 256, 0, stream>>>(x, xT);
  k_wfrag<<<3072, 256, 0, stream>>>(W_ih, W_hh, Wf);

  void* args[8] = {&xT, &Wf, &hbuf, &ctrs, &b_ih, &b_hh, &Wout, &part};
  hipLaunchCooperativeKernel((const void*)k_lstm, dim3(256), dim3(512), args, 0, stream);

  k_out<<<128, 256, 0, stream>>>(part, bout, out);
}